// Round 6
// baseline (366.962 us; speedup 1.0000x reference)
//
#include <hip/hip_runtime.h>
#include <hip/hip_bf16.h>
#include <stdint.h>

// HydraAttention pipeline. Inputs fp32, output fp32.
//   cvt   : query, w_qkv, w_out  fp32 -> bf16
//   GEMM1 : qkv = query @ w_qkv^T + b_qkv  -> q,k,v bf16
//   attn  : per t: S = (q_hat k_hat^T)/8, softmax, ws = P v
//   GEMM2 : out = ws @ w_out^T + b_out -> fp32
//
// GEMMs: 256x256 tile, BK=64, 8 waves (2Mx4N), double-buffered 128KB LDS,
// 8-phase schedule over 2 K-tiles. R6: REGISTER READ-AHEAD — every phase's
// MFMA consumes fragments ds_read in an EARLIER phase (except buffer-switch
// p1/p5), so LDS service overlaps the matrix pipe instead of serializing
// with it. Quadrant order (0,0),(0,2),(4,2),(4,0); frags split afA/afB/
// bf01/bf23. Drain points: B-region reads all issued @p1 and consumed by
// p1/p2 MFMAs => drained cluster-wide at p2's trailing barrier => stage B
// @p3. A-region reads @p1,p2, consumed by p3 MFMA => stage A @p4. vmcnt(8)
// at p4/p8-end retires exactly the tile the next half reads (verified for
// prologue / steady state / last iteration). Rule-18 sched_barrier kept on
// vmcnt waits only.

typedef __attribute__((ext_vector_type(8))) short short8;   // 8 x bf16
typedef __attribute__((ext_vector_type(4))) float floatx4;  // MFMA C/D

__device__ __forceinline__ float bf2f(short s) {
  union { unsigned u; float f; } v;
  v.u = ((unsigned)(unsigned short)s) << 16;
  return v.f;
}
__device__ __forceinline__ short f2bf(float x) {
  union { float f; unsigned u; } v; v.f = x;
  unsigned u = v.u;
  unsigned r = (u + 0x7fffu + ((u >> 16) & 1u)) >> 16;  // RNE
  return (short)r;
}
__device__ __forceinline__ short8 pack_bf8(float4 lo, float4 hi) {
  short8 r;
  r[0] = f2bf(lo.x); r[1] = f2bf(lo.y); r[2] = f2bf(lo.z); r[3] = f2bf(lo.w);
  r[4] = f2bf(hi.x); r[5] = f2bf(hi.y); r[6] = f2bf(hi.z); r[7] = f2bf(hi.w);
  return r;
}

// Async global->LDS, 16 B per lane. LDS dest = wave-uniform base + lane*16.
__device__ __forceinline__ void gl2lds16(const short* g, short* l) {
  __builtin_amdgcn_global_load_lds(
      (const __attribute__((address_space(1))) void*)g,
      (__attribute__((address_space(3))) void*)l, 16, 0, 0);
}

// ---------------------------------------------------------------------------
// fp32 -> bf16 elementwise, 8 elems/thread. n8 = n/8.
// ---------------------------------------------------------------------------
__global__ __launch_bounds__(256)
void cvt_bf16(const float* __restrict__ in, short* __restrict__ out, int n8) {
  const int i = blockIdx.x * 256 + threadIdx.x;
  if (i < n8) {
    float4 a = ((const float4*)in)[2 * i];
    float4 b = ((const float4*)in)[2 * i + 1];
    ((short8*)out)[i] = pack_bf8(a, b);
  }
}

// ---------------------------------------------------------------------------
// Pure-bf16 GEMM (B^T form): C[m,n] = sum_k A[m,k]*W[n,k] + bias[n]
// EPI=0: scatter n>>10 -> {o0,o1,o2} bf16 (q/k/v). EPI=1: fp32 out w/ remap.
// Requires K % 128 == 0 (NT even).
// ---------------------------------------------------------------------------

// MFMA quadrant: k-slice outer; operand arrays explicit (read-ahead sets).
#define DO_MFMA(BI, BJ, AF, BF)                                              \
  __builtin_amdgcn_s_setprio(1);                                             \
  _Pragma("unroll")                                                          \
  for (int k = 0; k < 2; ++k)                                                \
    _Pragma("unroll")                                                        \
    for (int i = 0; i < 4; ++i)                                              \
      _Pragma("unroll")                                                      \
      for (int j = 0; j < 2; ++j)                                            \
        acc[(BI) + i][(BJ) + j] = __builtin_amdgcn_mfma_f32_16x16x32_bf16(   \
            (AF)[i][k], (BF)[j][k], acc[(BI) + i][(BJ) + j], 0, 0, 0);       \
  __builtin_amdgcn_s_setprio(0);

#define READ_AF(DST, SRC, MH)                                                \
  _Pragma("unroll")                                                          \
  for (int i = 0; i < 4; ++i) {                                              \
    DST[i][0] = *(const short8*)((SRC) + aRow + (MH) * 4096 + i * 1024 + kOff0); \
    DST[i][1] = *(const short8*)((SRC) + aRow + (MH) * 4096 + i * 1024 + kOff1); \
  }

#define READ_BF(DST, SRC, OFF)                                               \
  _Pragma("unroll")                                                          \
  for (int j = 0; j < 2; ++j) {                                              \
    DST[j][0] = *(const short8*)((SRC) + bRow + (OFF) + j * 1024 + kOff0);   \
    DST[j][1] = *(const short8*)((SRC) + bRow + (OFF) + j * 1024 + kOff1);   \
  }

#define FENCE asm volatile("" ::: "memory")
#define BAR FENCE; __builtin_amdgcn_s_barrier(); FENCE
#define WAIT_VM(N)                                                           \
  asm volatile("s_waitcnt vmcnt(" #N ")" ::: "memory");                      \
  __builtin_amdgcn_sched_barrier(0)

template <int EPI>
__global__ __launch_bounds__(512, 2)
void gemm_bf(const short* __restrict__ A, const short* __restrict__ W,
             const float* __restrict__ bias, void* __restrict__ o0,
             void* __restrict__ o1, void* __restrict__ o2, int K,
             int rowbase, int tsh) {
  // [buf][A/B][256 rows][64 k] bf16 = 128 KiB total.
  __shared__ __align__(16) short lds[2][2][16384];

  const int tid  = threadIdx.x;
  const int lane = tid & 63, wave = tid >> 6;
  const int l15  = lane & 15, quad = lane >> 4;
  const int wm   = wave >> 2, wn = wave & 3;   // 2 x 4 wave grid

  // Bijective XCD-aware block swizzle (m204 form; works for any nwg).
  const int gx   = gridDim.x;
  const int nwg  = gx * gridDim.y;
  const int orig = blockIdx.y * gx + blockIdx.x;
  const int qq = nwg >> 3, rr = nwg & 7;
  const int xcd = orig & 7, off = orig >> 3;
  const int wgid = (xcd < rr ? xcd * (qq + 1) : rr * (qq + 1) + (xcd - rr) * qq) + off;
  const int m0 = (wgid / gx) * 256, n0 = (wgid % gx) * 256;

  // --- staging geometry: per half-tile (128 rows x 64 k = 16KB) each thread
  // issues 2 x 16B. Linear LDS dest; SOURCE column pre-swizzled with the
  // read-side involution byte ^= ((row&7)<<4).
  const int rl0 = tid >> 3;                  // row within half for call 0 (0..63)
  const int ic0 = (tid & 7) << 4;            // in-row byte (0..112)
  const int sc  = ic0 ^ ((rl0 & 7) << 4);    // swizzled src col byte
  const short* Ag = A + (size_t)(m0 + rl0) * K + (sc >> 1);
  const short* Wg = W + (size_t)(n0 + rl0) * K + (sc >> 1);

  const int NT = K >> 6;   // K-tiles of 64 (must be even)

  auto stageA = [&](int buf, int h, int t) {
    const short* g = Ag + (size_t)(h * 128) * K + t * 64;
    short* d = &lds[buf][0][h * 8192 + tid * 8];
    gl2lds16(g, d);
    gl2lds16(g + (size_t)64 * K, d + 4096);
  };
  auto stageB = [&](int buf, int h, int t) {
    const short* g = Wg + (size_t)(h * 128) * K + t * 64;
    short* d = &lds[buf][1][h * 8192 + tid * 8];
    gl2lds16(g, d);
    gl2lds16(g + (size_t)64 * K, d + 4096);
  };

  // --- fragment read geometry (row&7 == l15&7 for all frag rows) ---
  const int xsw   = (l15 & 7) << 4;
  const int aRow  = (wm * 128 + l15) * 64;            // shorts
  const int bRow  = (wn * 64 + l15) * 64;
  const int kOff0 = ((quad * 16) ^ xsw) >> 1;
  const int kOff1 = ((64 + quad * 16) ^ xsw) >> 1;

  floatx4 acc[8][4] = {};

  // Prologue: tiles 0 (buf0) and 1 (buf1) fully staged (16 loads).
  // vmcnt(8): tile 0 landed; tile 1's 8 loads may remain in flight.
  stageA(0, 0, 0); stageA(0, 1, 0); stageB(0, 0, 0); stageB(0, 1, 0);
  stageB(1, 0, 1); stageB(1, 1, 1); stageA(1, 0, 1); stageA(1, 1, 1);
  WAIT_VM(8);
  BAR;

  short8 afA[4][2], afB[4][2], bf01[2][2], bf23[2][2];
  const short* const A0 = lds[0][0]; const short* const B0 = lds[0][1];
  const short* const A1 = lds[1][0]; const short* const B1 = lds[1][1];

  const int NI = NT >> 1;
  for (int it = 0; it < NI; ++it) {
    const bool st = (it + 1 < NI);      // tiles 2it+2 / 2it+3 exist
    const int e2 = 2 * it + 2, o3 = 2 * it + 3;

    // p1: read ALL buf0 B frags + A-first (16 reads); MFMA(0,0) same-phase
    //     (unavoidable: buf0 only valid after prior p8's vmcnt+barrier).
    READ_AF(afA, A0, 0); READ_BF(bf01, B0, 0); READ_BF(bf23, B0, 2048);
    BAR;
    DO_MFMA(0, 0, afA, bf01);
    BAR;

    // p2: read A-second (8 reads, consumed @p3); MFMA(0,2) on resident frags.
    READ_AF(afB, A0, 1);
    BAR;
    DO_MFMA(0, 2, afA, bf23);
    BAR;

    // p3: stage B(e2)->buf0 (B0 reads all drained by p2's trailing barrier);
    //     MFMA(4,2) on afB (read @p2, overlapped) + bf23 (resident).
    if (st) { stageB(0, 0, e2); stageB(0, 1, e2); }
    DO_MFMA(4, 2, afB, bf23);
    BAR;

    // p4: stage A(e2)->buf0 (A0 reads drained by p3's barrier); MFMA(4,0)
    //     fully resident. vmcnt(8) retires tile 2it+1 (staged p7/p8 prev),
    //     leaves e2's 8 loads in flight.
    if (st) { stageA(0, 0, e2); stageA(0, 1, e2); }
    DO_MFMA(4, 0, afB, bf01);
    if (st) { WAIT_VM(8); } else { WAIT_VM(0); }
    BAR;

    // p5-p8: mirror on buf1 (tile 2it+1), staging o3.
    READ_AF(afA, A1, 0); READ_BF(bf01, B1, 0); READ_BF(bf23, B1, 2048);
    BAR;
    DO_MFMA(0, 0, afA, bf01);
    BAR;

    READ_AF(afB, A1, 1);
    BAR;
    DO_MFMA(0, 2, afA, bf23);
    BAR;

    if (st) { stageB(1, 0, o3); stageB(1, 1, o3); }
    DO_MFMA(4, 2, afB, bf23);
    BAR;

    if (st) { stageA(1, 0, o3); stageA(1, 1, o3); }
    DO_MFMA(4, 0, afB, bf01);
    if (st) { WAIT_VM(8); }   // retires e2 before next p1 reads buf0
    BAR;
  }

  // Epilogue. C/D layout: col = lane&15 (n), row = quad*4 + r (m).
  // Row-grouped store order: per row, all 4 column-chunks back-to-back.
  if constexpr (EPI == 0) {
    float bv[4]; int ee[4]; short* op[4];
#pragma unroll
    for (int j = 0; j < 4; ++j) {
      const int n = n0 + wn * 64 + j * 16 + l15;
      bv[j] = bias[n];
      const int which = n >> 10;
      ee[j] = n & 1023;
      op[j] = (which == 0) ? (short*)o0 : ((which == 1) ? (short*)o1 : (short*)o2);
    }
#pragma unroll
    for (int i = 0; i < 8; ++i)
#pragma unroll
      for (int r = 0; r < 4; ++r) {
        const int mloc = m0 + wm * 128 + i * 16 + quad * 4 + r;
        const size_t rowoff = (size_t)mloc * 1024;
#pragma unroll
        for (int j = 0; j < 4; ++j)
          op[j][rowoff + ee[j]] = f2bf(acc[i][j][r] + bv[j]);
      }
  } else {
    float bv[4]; int nn[4];
#pragma unroll
    for (int j = 0; j < 4; ++j) {
      nn[j] = n0 + wn * 64 + j * 16 + l15;
      bv[j] = bias[nn[j]];
    }
#pragma unroll
    for (int i = 0; i < 8; ++i)
#pragma unroll
      for (int r = 0; r < 4; ++r) {
        const int mloc = m0 + wm * 128 + i * 16 + quad * 4 + r;
        const int g = ((mloc >> tsh) << 11) + rowbase + (mloc & ((1 << tsh) - 1));
        const size_t rowoff = (size_t)g * 1024;
#pragma unroll
        for (int j = 0; j < 4; ++j)
          ((float*)o0)[rowoff + nn[j]] = acc[i][j][r] + bv[j];
      }
  }
}

// ---------------------------------------------------------------------------
// Attention: one block (256 thr, 4 waves) per local t'. (unchanged from R5)
// ---------------------------------------------------------------------------
__global__ __launch_bounds__(256)
void attn_kernel(const short* __restrict__ qb, const short* __restrict__ kb,
                 const short* __restrict__ vb, short* __restrict__ wsb, int tch) {
  __shared__ __align__(16) char smem[55296];
  short* qs  = (short*)smem;             // [128][72]
  short* ks  = (short*)(smem + 18432);   // [128][72]
  short* Ps  = (short*)smem;             // [128][136] (overlays qs/ks after S)
  short* vt  = (short*)(smem + 36864);   // [64][136]
  float* rsq = (float*)(smem + 54272);   // [128]
  float* rsk = rsq + 128;                // [128]

  const int tp   = blockIdx.x;
  const int tid  = threadIdx.x;
  const int lane = tid & 63, wave = tid >> 6;
  const int l15  = lane & 15, quad = lane >> 4;
  const size_t base = (size_t)tp * 8192;

#pragma unroll
  for (int it = 0; it < 4; it++) {
    const int c = tid + it * 256;
    const int row = c >> 3, c8 = (c & 7) * 8;
    uint4 qv = *(const uint4*)(qb + base + row * 64 + c8);
    uint4 kv = *(const uint4*)(kb + base + row * 64 + c8);
    *(uint4*)(qs + row * 72 + c8) = qv;
    *(uint4*)(ks + row * 72 + c8) = kv;
    short tmp[8];
    *(uint4*)tmp = *(const uint4*)(vb + base + row * 64 + c8);
#pragma unroll
    for (int j = 0; j < 8; j++) vt[(c8 + j) * 136 + row] = tmp[j];
  }
  __syncthreads();

  {
    const short* src = (tid < 128) ? qs : ks;
    const int r = tid & 127;
    const short8* rp = (const short8*)(src + r * 72);
    float s = 0.f;
#pragma unroll
    for (int k8 = 0; k8 < 8; k8++) {
      short8 v = rp[k8];
#pragma unroll
      for (int j = 0; j < 8; j++) { float x = bf2f(v[j]); s += x * x; }
    }
    ((tid < 128) ? rsq : rsk)[r] = rsqrtf(s);
  }
  __syncthreads();

  const int wm = wave >> 1, wn = wave & 1;
  floatx4 acc[4][4] = {};
#pragma unroll
  for (int kk = 0; kk < 64; kk += 32) {
    short8 af[4], bfv[4];
#pragma unroll
    for (int i = 0; i < 4; i++)
      af[i] = *(const short8*)(qs + (wm * 64 + i * 16 + l15) * 72 + kk + quad * 8);
#pragma unroll
    for (int j = 0; j < 4; j++)
      bfv[j] = *(const short8*)(ks + (wn * 64 + j * 16 + l15) * 72 + kk + quad * 8);
#pragma unroll
    for (int i = 0; i < 4; i++)
#pragma unroll
      for (int j = 0; j < 4; j++)
        acc[i][j] = __builtin_amdgcn_mfma_f32_16x16x32_bf16(af[i], bfv[j], acc[i][j], 0, 0, 0);
  }
  __syncthreads();

#pragma unroll
  for (int i = 0; i < 4; i++)
#pragma unroll
    for (int j = 0; j < 4; j++)
#pragma unroll
      for (int r = 0; r < 4; r++) {
        const int a    = wm * 64 + i * 16 + quad * 4 + r;
        const int bcol = wn * 64 + j * 16 + l15;
        Ps[a * 136 + bcol] = f2bf(acc[i][j][r] * rsq[a] * rsk[bcol] * 0.125f);
      }
  __syncthreads();

  {
    const int r = tid >> 1, h = tid & 1;
    short8* rp = (short8*)(Ps + r * 136 + h * 64);
    short8 v[8];
    float mx = -1e30f;
#pragma unroll
    for (int k8 = 0; k8 < 8; k8++) {
      v[k8] = rp[k8];
#pragma unroll
      for (int j = 0; j < 8; j++) mx = fmaxf(mx, bf2f(v[k8][j]));
    }
    mx = fmaxf(mx, __shfl_xor(mx, 1, 64));
    float sum = 0.f;
#pragma unroll
    for (int k8 = 0; k8 < 8; k8++) {
      short8 o;
#pragma unroll
      for (int j = 0; j < 8; j++) {
        float p = __expf(bf2f(v[k8][j]) - mx);
        sum += p;
        o[j] = f2bf(p);
      }
      rp[k8] = o;
    }
    sum += __shfl_xor(sum, 1, 64);
    if (h == 0) rsq[r] = 1.0f / sum;
  }
  __syncthreads();

  floatx4 acc2[2][4] = {};
#pragma unroll
  for (int kb2 = 0; kb2 < 128; kb2 += 32) {
    short8 af[2], bfv[4];
#pragma unroll
    for (int ti = 0; ti < 2; ti++)
      af[ti] = *(const short8*)(Ps + (wave * 32 + ti * 16 + l15) * 136 + kb2 + quad * 8);
#pragma unroll
    for (int tj = 0; tj < 4; tj++)
      bfv[tj] = *(const short8*)(vt + (tj * 16 + l15) * 136 + kb2 + quad * 8);
#pragma unroll
    for (int ti = 0; ti < 2; ti++)
#pragma unroll
      for (int tj = 0; tj < 4; tj++)
        acc2[ti][tj] = __builtin_amdgcn_mfma_f32_16x16x32_bf16(af[ti], bfv[tj], acc2[ti][tj], 0, 0, 0);
  }

#pragma unroll
  for (int ti = 0; ti < 2; ti++)
#pragma unroll
    for (int tj = 0; tj < 4; tj++)
#pragma unroll
      for (int r = 0; r < 4; r++) {
        const int a = wave * 32 + ti * 16 + quad * 4 + r;
        const int d = tj * 16 + l15;
        const float v = acc2[ti][tj][r] * rsq[a];
        const int bz = a >> 4, h = a & 15;
        wsb[((size_t)bz * tch + tp) * 1024 + h * 64 + d] = f2bf(v);
      }
}

// ---------------------------------------------------------------------------
extern "C" void kernel_launch(void* const* d_in, const int* in_sizes, int n_in,
                              void* d_out, int out_size, void* d_ws, size_t ws_size,
                              hipStream_t stream) {
  const float* query = (const float*)d_in[0];
  // d_in[1] (key), d_in[2] (value) unused per reference semantics.
  const float* w_qkv = (const float*)d_in[3];
  const float* b_qkv = (const float*)d_in[4];
  const float* w_out = (const float*)d_in[5];
  const float* b_out = (const float*)d_in[6];
  float* out = (float*)d_out;

  // Chunk count C: footprint = 8.4MB weights + 4*(16384/C)*2048 B.
  // Cap at 64 so Mc stays a multiple of 256 (GEMM tile).
  int C = 64;
  for (int c = 1; c <= 64; c <<= 1) {
    if ((size_t)(8388608 + 134217728 / c) <= ws_size) { C = c; break; }
  }
  const int Mc  = 16384 / C;   // rows per chunk (multiple of 256)
  const int TCH = 2048 / C;    // t's per chunk
  int tsh = 0; while ((1 << tsh) < TCH) tsh++;

  short* wqkvb = (short*)d_ws;            // 3072*1024 bf16
  short* woutb = wqkvb + 3145728;         // 1024*1024 bf16
  short* qbuf  = woutb + 1048576;
  short* kbuf  = qbuf + (size_t)Mc * 1024;
  short* vbuf  = kbuf + (size_t)Mc * 1024;
  short* wsb   = vbuf + (size_t)Mc * 1024;   // overlay: bf16 query chunk, then attn out

  cvt_bf16<<<3145728 / 8 / 256, 256, 0, stream>>>(w_qkv, wqkvb, 3145728 / 8);
  cvt_bf16<<<1048576 / 8 / 256, 256, 0, stream>>>(w_out, woutb, 1048576 / 8);

  for (int c = 0; c < C; c++) {
    const int n8 = Mc * 1024 / 8;
    cvt_bf16<<<(n8 + 255) / 256, 256, 0, stream>>>(query + (size_t)c * Mc * 1024, wsb, n8);
    gemm_bf<0><<<dim3(12, Mc / 256), 512, 0, stream>>>(
        wsb, wqkvb, b_qkv, qbuf, kbuf, vbuf, 1024, 0, 0);
    attn_kernel<<<TCH, 256, 0, stream>>>(qbuf, kbuf, vbuf, wsb, TCH);
    gemm_bf<1><<<dim3(4, Mc / 256), 512, 0, stream>>>(
        wsb, woutb, b_out, out, nullptr, nullptr, 1024, c * TCH, tsh);
  }
}